// Round 1
// baseline (290.856 us; speedup 1.0000x reference)
//
#include <hip/hip_runtime.h>
#include <stdint.h>

// ---------------- problem constants ----------------
constexpr int Wd  = 640;
constexpr int Hd  = 480;
constexpr int Bd  = 8;
constexpr int Gd  = 368640;          // int(B*H*W*0.15)
constexpr int Nd  = Bd * Gd;         // 2,949,120
constexpr int HWd = Hd * Wd;
constexpr int GRID1 = Gd / 256;      // 1440 exactly

// ---------------- workspace layout (bytes) ----------------
#define WS_SUM_ALL  0      // double: sum of all masked L
#define WS_SUM_LESS 8      // double: sum of masked L with bits < vbits
#define WS_N        16     // u32: masked count
#define WS_DROP     20     // u32: n >> 2
#define WS_BIN1     24     // u32
#define WS_TGT1     28     // u32
#define WS_CL1      32     // u32
#define WS_BIN2     36     // u32
#define WS_TGT2     40     // u32
#define WS_CL2      44     // u32
#define WS_BIN3     48     // u32
#define WS_TGT3     52     // u32 (scratch)
#define WS_CLESS    56     // u32: final count strictly-less than v
#define WS_DONE     60     // u32: completion counter for last-block finalize
#define HIST1_OFF   64                  // 4096 u32
#define HIST2_OFF   (HIST1_OFF + 4096*4)
#define HIST3_OFF   (HIST2_OFF + 4096*4)  // 256 u32
#define CTRL_BYTES  (HIST3_OFF + 256*4)
#define LM_OFF      36864               // float Lm[Nd]

// ---------------- kernel 1: per-sample L + mask + hist1 + count + sum ----------------
__global__ __launch_bounds__(256) void k_compute(
    const float* __restrict__ gt, const float* __restrict__ pd,
    const int* __restrict__ p1x, const int* __restrict__ p1y,
    const int* __restrict__ p2x, const int* __restrict__ p2y,
    const int* __restrict__ p3x, const int* __restrict__ p3y,
    unsigned char* __restrict__ ws)
{
    __shared__ unsigned lh[4096];
    __shared__ double   ssum[256];
    __shared__ unsigned scnt[256];
    const int t = threadIdx.x;
    for (int k = t; k < 4096; k += 256) lh[k] = 0u;
    __syncthreads();

    const int g = blockIdx.x * 256 + t;
    const int x1 = p1x[g], y1 = p1y[g];
    const int x2 = p2x[g], y2 = p2y[g];
    const int x3 = p3x[g], y3 = p3y[g];
    const int o1 = y1 * Wd + x1, o2 = y2 * Wd + x2, o3 = y3 * Wd + x3;
    const float u1 = (float)x1 - 320.0f, v1 = (float)y1 - 240.0f;
    const float u2 = (float)x2 - 320.0f, v2 = (float)y2 - 240.0f;
    const float u3 = (float)x3 - 320.0f, v3 = (float)y3 - 240.0f;
    constexpr float RF = 1.0f / 519.0f;

    float* __restrict__ Lm = (float*)(ws + LM_OFF);
    double   lsum = 0.0;
    unsigned lcnt = 0u;

    for (int b = 0; b < Bd; ++b) {
        const int base = b * HWd;
        const float d1 = gt[base + o1], d2 = gt[base + o2], d3 = gt[base + o3];
        const float e1 = pd[base + o1], e2 = pd[base + o2], e3 = pd[base + o3];

        // gt points: x=(px-U0)*|d|/FX, y=(py-V0)*|d|/FY, z=d
        const float a1 = fabsf(d1) * RF, a2 = fabsf(d2) * RF, a3 = fabsf(d3) * RF;
        const float gx1 = u1 * a1, gy1 = v1 * a1;
        const float gx2 = u2 * a2, gy2 = v2 * a2;
        const float gx3 = u3 * a3, gy3 = v3 * a3;

        // difference vectors D0=d12, D1=d13, D2=d23
        const float D0x = gx2 - gx1, D0y = gy2 - gy1, D0z = d2 - d1;
        const float D1x = gx3 - gx1, D1y = gy3 - gy1, D1z = d3 - d1;
        const float D2x = gx3 - gx2, D2y = gy3 - gy2, D2z = d3 - d2;

        // gram + norms for the cos mask
        const float e00 = D0x*D0x + D0y*D0y + D0z*D0z;
        const float e11 = D1x*D1x + D1y*D1y + D1z*D1z;
        const float e22 = D2x*D2x + D2y*D2y + D2z*D2z;
        const float e01 = D0x*D1x + D0y*D1y + D0z*D1z;
        const float e02 = D0x*D2x + D0y*D2y + D0z*D2z;
        const float e12 = D1x*D2x + D1y*D2y + D1z*D2z;
        const float n0 = sqrtf(e00), n1 = sqrtf(e11), n2 = sqrtf(e22);
        // |e/(nm+1e-8)| > 0.867  <=>  |e| > 0.867*(nm+1e-8)   (nm+eps > 0)
        constexpr float DC = 0.867f;
        int cnt = 0;
        cnt += (fabsf(e00) > DC * (n0*n0 + 1e-8f));
        cnt += (fabsf(e11) > DC * (n1*n1 + 1e-8f));
        cnt += (fabsf(e22) > DC * (n2*n2 + 1e-8f));
        cnt += 2 * (fabsf(e01) > DC * (n0*n1 + 1e-8f));
        cnt += 2 * (fabsf(e02) > DC * (n0*n2 + 1e-8f));
        cnt += 2 * (fabsf(e12) > DC * (n1*n2 + 1e-8f));
        const bool mask_cos = cnt > 3;

        const bool mx = (fabsf(D0x) < 0.01f) | (fabsf(D1x) < 0.01f) | (fabsf(D2x) < 0.01f);
        const bool my = (fabsf(D0y) < 0.01f) | (fabsf(D1y) < 0.01f) | (fabsf(D2y) < 0.01f);
        const bool mz = (fabsf(D0z) < 0.01f) | (fabsf(D1z) < 0.01f) | (fabsf(D2z) < 0.01f);
        const bool mask = !((mx && my && mz) || mask_cos);

        // pred points
        const float b1s = fabsf(e1) * RF, b2s = fabsf(e2) * RF, b3s = fabsf(e3) * RF;
        float qx1 = u1 * b1s, qy1 = v1 * b1s, qz1 = e1;
        float qx2 = u2 * b2s, qy2 = v2 * b2s, qz2 = e2;
        float qx3 = u3 * b3s, qy3 = v3 * b3s, qz3 = e3;
        // replicate the reference's zmask broadcast: z of point c == 0
        // sets COORDINATE ROW c of all points to 1e-4
        const bool zm0 = (qz1 == 0.0f), zm1 = (qz2 == 0.0f), zm2 = (qz3 == 0.0f);
        if (zm0) { qx1 = qx2 = qx3 = 1e-4f; }
        if (zm1) { qy1 = qy2 = qy3 = 1e-4f; }
        if (zm2) { qz1 = qz2 = qz3 = 1e-4f; }

        const float P0x = qx2 - qx1, P0y = qy2 - qy1, P0z = qz2 - qz1;
        const float P1x = qx3 - qx1, P1y = qy3 - qy1, P1z = qz3 - qz1;

        // normals (gt uses D0=d12, D1=d13)
        const float gnx = D0y * D1z - D0z * D1y;
        const float gny = D0z * D1x - D0x * D1z;
        const float gnz = D0x * D1y - D0y * D1x;
        const float dnx = P0y * P1z - P0z * P1y;
        const float dny = P0z * P1x - P0x * P1z;
        const float dnz = P0x * P1y - P0y * P1x;

        float gnn = sqrtf(gnx*gnx + gny*gny + gnz*gnz);
        float dnn = sqrtf(dnx*dnx + dny*dny + dnz*dnz);
        if (gnn == 0.0f) gnn = 0.01f;
        if (dnn == 0.0f) dnn = 0.01f;
        const float rg = 1.0f / gnn, rd = 1.0f / dnn;
        const float L = fabsf(gnx*rg - dnx*rd) + fabsf(gny*rg - dny*rd) + fabsf(gnz*rg - dnz*rd);

        Lm[b * Gd + g] = mask ? L : -1.0f;
        if (mask) {
            ++lcnt;
            lsum += (double)L;
            atomicAdd(&lh[__float_as_uint(L) >> 20], 1u);   // top 12 bits (sign=0)
        }
    }

    ssum[t] = lsum; scnt[t] = lcnt;
    __syncthreads();
    for (int s = 128; s > 0; s >>= 1) {
        if (t < s) { ssum[t] += ssum[t + s]; scnt[t] += scnt[t + s]; }
        __syncthreads();
    }
    if (t == 0) {
        atomicAdd((double*)(ws + WS_SUM_ALL), ssum[0]);
        atomicAdd((unsigned*)(ws + WS_N), scnt[0]);
    }
    unsigned* __restrict__ h1 = (unsigned*)(ws + HIST1_OFF);
    for (int k = t; k < 4096; k += 256) {
        const unsigned c = lh[k];
        if (c) atomicAdd(&h1[k], c);
    }
}

// ---------------- radix-select helper: single 256-thread block ----------------
template <int NB>
__device__ void select_in_block(const unsigned* __restrict__ hist, unsigned target,
                                unsigned cless_base, unsigned* out_bin,
                                unsigned* out_tnext, unsigned* out_cless)
{
    constexpr int PER = NB / 256;
    __shared__ unsigned part[256];
    const int t = threadIdx.x;
    unsigned loc[PER];
    unsigned s = 0;
#pragma unroll
    for (int k = 0; k < PER; ++k) { loc[k] = hist[t * PER + k]; s += loc[k]; }
    part[t] = s;
    __syncthreads();
    for (int off = 1; off < 256; off <<= 1) {
        const unsigned add = (t >= off) ? part[t - off] : 0u;
        __syncthreads();
        part[t] += add;
        __syncthreads();
    }
    const unsigned incl = part[t];
    const unsigned excl = incl - s;
    if (incl >= target && excl < target) {
        unsigned cum = excl;
#pragma unroll
        for (int k = 0; k < PER; ++k) {
            const unsigned c = loc[k];
            if (cum + c >= target) {
                *out_bin   = (unsigned)(t * PER + k);
                *out_tnext = target - cum;
                *out_cless = cless_base + cum;
                break;
            }
            cum += c;
        }
    }
}

__global__ __launch_bounds__(256) void k_sel1(unsigned char* __restrict__ ws)
{
    const unsigned n = *(const unsigned*)(ws + WS_N);
    const unsigned drop = n >> 2;
    if (threadIdx.x == 0) *(unsigned*)(ws + WS_DROP) = drop;
    if (drop == 0) {
        if (threadIdx.x == 0) {
            *(unsigned*)(ws + WS_BIN1) = 0xFFFFFFFFu;
            *(unsigned*)(ws + WS_TGT1) = 0u;
            *(unsigned*)(ws + WS_CL1)  = 0u;
        }
        return;
    }
    select_in_block<4096>((const unsigned*)(ws + HIST1_OFF), drop, 0u,
                          (unsigned*)(ws + WS_BIN1), (unsigned*)(ws + WS_TGT1),
                          (unsigned*)(ws + WS_CL1));
}

__global__ __launch_bounds__(256) void k_hist2(unsigned char* __restrict__ ws)
{
    __shared__ unsigned lh[4096];
    const int t = threadIdx.x;
    for (int k = t; k < 4096; k += 256) lh[k] = 0u;
    __syncthreads();
    const unsigned bin1 = *(const unsigned*)(ws + WS_BIN1);
    const float* __restrict__ Lm = (const float*)(ws + LM_OFF);
    const int stride = gridDim.x * blockDim.x;
    for (int i = blockIdx.x * 256 + t; i < Nd; i += stride) {
        const unsigned u = __float_as_uint(Lm[i]);
        if (!(u & 0x80000000u) && (u >> 20) == bin1)
            atomicAdd(&lh[(u >> 8) & 0xFFFu], 1u);
    }
    __syncthreads();
    unsigned* __restrict__ h2 = (unsigned*)(ws + HIST2_OFF);
    for (int k = t; k < 4096; k += 256) {
        const unsigned c = lh[k];
        if (c) atomicAdd(&h2[k], c);
    }
}

__global__ __launch_bounds__(256) void k_sel2(unsigned char* __restrict__ ws)
{
    const unsigned drop = *(const unsigned*)(ws + WS_DROP);
    if (drop == 0) {
        if (threadIdx.x == 0) {
            *(unsigned*)(ws + WS_BIN2) = 0xFFFFFFFFu;
            *(unsigned*)(ws + WS_TGT2) = 0u;
            *(unsigned*)(ws + WS_CL2)  = 0u;
        }
        return;
    }
    const unsigned tgt1 = *(const unsigned*)(ws + WS_TGT1);
    const unsigned cl1  = *(const unsigned*)(ws + WS_CL1);
    select_in_block<4096>((const unsigned*)(ws + HIST2_OFF), tgt1, cl1,
                          (unsigned*)(ws + WS_BIN2), (unsigned*)(ws + WS_TGT2),
                          (unsigned*)(ws + WS_CL2));
}

__global__ __launch_bounds__(256) void k_hist3(unsigned char* __restrict__ ws)
{
    __shared__ unsigned lh[256];
    const int t = threadIdx.x;
    lh[t] = 0u;
    __syncthreads();
    const unsigned bin1 = *(const unsigned*)(ws + WS_BIN1);
    const unsigned bin2 = *(const unsigned*)(ws + WS_BIN2);
    const float* __restrict__ Lm = (const float*)(ws + LM_OFF);
    const int stride = gridDim.x * blockDim.x;
    for (int i = blockIdx.x * 256 + t; i < Nd; i += stride) {
        const unsigned u = __float_as_uint(Lm[i]);
        if (!(u & 0x80000000u) && (u >> 20) == bin1 && ((u >> 8) & 0xFFFu) == bin2)
            atomicAdd(&lh[u & 0xFFu], 1u);
    }
    __syncthreads();
    unsigned* __restrict__ h3 = (unsigned*)(ws + HIST3_OFF);
    const unsigned c = lh[t];
    if (c) atomicAdd(&h3[t], c);
}

__global__ __launch_bounds__(256) void k_sel3(unsigned char* __restrict__ ws)
{
    const unsigned drop = *(const unsigned*)(ws + WS_DROP);
    if (drop == 0) {
        if (threadIdx.x == 0) {
            *(unsigned*)(ws + WS_BIN3)  = 0u;
            *(unsigned*)(ws + WS_CLESS) = 0u;
        }
        return;
    }
    const unsigned tgt2 = *(const unsigned*)(ws + WS_TGT2);
    const unsigned cl2  = *(const unsigned*)(ws + WS_CL2);
    select_in_block<256>((const unsigned*)(ws + HIST3_OFF), tgt2, cl2,
                         (unsigned*)(ws + WS_BIN3), (unsigned*)(ws + WS_TGT3),
                         (unsigned*)(ws + WS_CLESS));
}

// ---------------- final: sum of masked values strictly below v, then finalize ----------------
__global__ __launch_bounds__(256) void k_sumless(unsigned char* __restrict__ ws,
                                                 float* __restrict__ out)
{
    __shared__ double ssum[256];
    const int t = threadIdx.x;
    const unsigned drop = *(const unsigned*)(ws + WS_DROP);
    unsigned vbits = 0u;
    if (drop) {
        const unsigned b1 = *(const unsigned*)(ws + WS_BIN1);
        const unsigned b2 = *(const unsigned*)(ws + WS_BIN2);
        const unsigned b3 = *(const unsigned*)(ws + WS_BIN3);
        vbits = (b1 << 20) | (b2 << 8) | b3;
    }
    const float* __restrict__ Lm = (const float*)(ws + LM_OFF);
    const int stride = gridDim.x * blockDim.x;
    double ls = 0.0;
    for (int i = blockIdx.x * 256 + t; i < Nd; i += stride) {
        const unsigned u = __float_as_uint(Lm[i]);
        if (!(u & 0x80000000u) && u < vbits) ls += (double)__uint_as_float(u);
    }
    ssum[t] = ls;
    __syncthreads();
    for (int s = 128; s > 0; s >>= 1) {
        if (t < s) ssum[t] += ssum[t + s];
        __syncthreads();
    }
    if (t == 0) {
        atomicAdd((double*)(ws + WS_SUM_LESS), ssum[0]);
        __threadfence();
        const unsigned prev = atomicAdd((unsigned*)(ws + WS_DONE), 1u);
        if (prev == gridDim.x - 1) {
            const double sl = atomicAdd((double*)(ws + WS_SUM_LESS), 0.0);  // coherent read
            const double sa = *(const double*)(ws + WS_SUM_ALL);
            const unsigned n     = *(const unsigned*)(ws + WS_N);
            const unsigned cless = drop ? *(const unsigned*)(ws + WS_CLESS) : 0u;
            const double v = (double)__uint_as_float(vbits);
            const double dropped = sl + v * (double)(drop - cless);
            const unsigned keep = n - drop;
            const double denom = (double)(keep > 0u ? keep : 1u);
            out[0] = (float)((sa - dropped) / denom);
        }
    }
}

extern "C" void kernel_launch(void* const* d_in, const int* in_sizes, int n_in,
                              void* d_out, int out_size, void* d_ws, size_t ws_size,
                              hipStream_t stream)
{
    const float* gt  = (const float*)d_in[0];
    const float* pd  = (const float*)d_in[1];
    const int*   p1x = (const int*)d_in[2];
    const int*   p1y = (const int*)d_in[3];
    const int*   p2x = (const int*)d_in[4];
    const int*   p2y = (const int*)d_in[5];
    const int*   p3x = (const int*)d_in[6];
    const int*   p3y = (const int*)d_in[7];
    unsigned char* ws = (unsigned char*)d_ws;
    float* out = (float*)d_out;

    hipMemsetAsync(ws, 0, CTRL_BYTES, stream);
    k_compute<<<dim3(GRID1), dim3(256), 0, stream>>>(gt, pd, p1x, p1y, p2x, p2y, p3x, p3y, ws);
    k_sel1   <<<dim3(1),     dim3(256), 0, stream>>>(ws);
    k_hist2  <<<dim3(GRID1), dim3(256), 0, stream>>>(ws);
    k_sel2   <<<dim3(1),     dim3(256), 0, stream>>>(ws);
    k_hist3  <<<dim3(GRID1), dim3(256), 0, stream>>>(ws);
    k_sel3   <<<dim3(1),     dim3(256), 0, stream>>>(ws);
    k_sumless<<<dim3(GRID1), dim3(256), 0, stream>>>(ws, out);
}

// Round 2
// 169.695 us; speedup vs baseline: 1.7140x; 1.7140x over previous
//
#include <hip/hip_runtime.h>
#include <stdint.h>

// ---------------- problem constants ----------------
constexpr int Wd  = 640;
constexpr int Hd  = 480;
constexpr int Bd  = 8;
constexpr int Gd  = 368640;          // int(B*H*W*0.15)
constexpr int Nd  = Bd * Gd;         // 2,949,120
constexpr int HWd = Hd * Wd;         // 307200
constexpr int GRID1 = Gd / 256;      // 1440 exactly
constexpr int GRIDP = HWd / 256;     // 1200 exactly

// ---------------- workspace layout (bytes) ----------------
// scalars
#define WS_SUM_ALL  0      // double: sum of all masked L
#define WS_SUM_LESS 8      // double: sum of masked L with top12 < bin1
#define WS_N        16     // u32: masked count
#define WS_DROP     20     // u32: n >> 2
#define WS_BIN1     24     // u32
#define WS_TGT1     28     // u32: rank within bin1
// histograms
#define HIST1_OFF   64                      // 4096 u32 (top 12 bits)
#define H2C_OFF     (HIST1_OFF + 4096*4)    // 4096 u32 (bits [19:8] within bin1)
#define H2S_OFF     (H2C_OFF  + 4096*4)     // 4096 double (per-bin value sums)
#define CTRL_BYTES  (H2S_OFF  + 4096*8)     // = 65600
// big buffers
#define PACK_OFF    65664                   // float pk[HWd][8][2]  (64B/pixel, 64B-aligned)
#define LM_OFF      (PACK_OFF + HWd*16*4)   // float Lm[Nd]

// ---------------- kernel 0: repack depth to pixel-major, batch-minor ----------------
// pk[o*16 + b*2 + 0] = gt[b*HW + o] ; pk[o*16 + b*2 + 1] = pd[b*HW + o]
// One pixel's 8 (gt,pd) pairs = exactly one 64B cache line.
__global__ __launch_bounds__(256) void k_pack(const float* __restrict__ gt,
                                              const float* __restrict__ pd,
                                              float* __restrict__ pk)
{
    const int o = blockIdx.x * 256 + threadIdx.x;
    float v[16];
#pragma unroll
    for (int b = 0; b < Bd; ++b) {
        v[2 * b]     = gt[b * HWd + o];
        v[2 * b + 1] = pd[b * HWd + o];
    }
    float4* __restrict__ dst = (float4*)(pk + (size_t)o * 16);
#pragma unroll
    for (int c = 0; c < 4; ++c)
        dst[c] = make_float4(v[4 * c], v[4 * c + 1], v[4 * c + 2], v[4 * c + 3]);
}

// ---------------- kernel 1: per-sample L + mask + hist1 + count + sum ----------------
__global__ __launch_bounds__(256) void k_compute(
    const int* __restrict__ p1x, const int* __restrict__ p1y,
    const int* __restrict__ p2x, const int* __restrict__ p2y,
    const int* __restrict__ p3x, const int* __restrict__ p3y,
    unsigned char* __restrict__ ws)
{
    __shared__ unsigned lh[4096];
    __shared__ double   ssum[256];
    __shared__ unsigned scnt[256];
    const int t = threadIdx.x;
    for (int k = t; k < 4096; k += 256) lh[k] = 0u;
    __syncthreads();

    const int g = blockIdx.x * 256 + t;
    const int x1 = p1x[g], y1 = p1y[g];
    const int x2 = p2x[g], y2 = p2y[g];
    const int x3 = p3x[g], y3 = p3y[g];
    const int o1 = y1 * Wd + x1, o2 = y2 * Wd + x2, o3 = y3 * Wd + x3;
    const float u1 = (float)x1 - 320.0f, v1 = (float)y1 - 240.0f;
    const float u2 = (float)x2 - 320.0f, v2 = (float)y2 - 240.0f;
    const float u3 = (float)x3 - 320.0f, v3 = (float)y3 - 240.0f;
    constexpr float RF = 1.0f / 519.0f;

    // one 64B line per sample point: all 8 batches' (gt,pd)
    const float4* __restrict__ pk4 = (const float4*)(ws + PACK_OFF);
    float4 A[4], Bv[4], Cv[4];
#pragma unroll
    for (int c = 0; c < 4; ++c) {
        A[c]  = pk4[(size_t)o1 * 4 + c];
        Bv[c] = pk4[(size_t)o2 * 4 + c];
        Cv[c] = pk4[(size_t)o3 * 4 + c];
    }
    const float* __restrict__ P1 = (const float*)A;
    const float* __restrict__ P2 = (const float*)Bv;
    const float* __restrict__ P3 = (const float*)Cv;

    float* __restrict__ Lm = (float*)(ws + LM_OFF);
    double   lsum = 0.0;
    unsigned lcnt = 0u;

#pragma unroll
    for (int b = 0; b < Bd; ++b) {
        const float d1 = P1[2 * b], e1 = P1[2 * b + 1];
        const float d2 = P2[2 * b], e2 = P2[2 * b + 1];
        const float d3 = P3[2 * b], e3 = P3[2 * b + 1];

        // gt points
        const float a1 = fabsf(d1) * RF, a2 = fabsf(d2) * RF, a3 = fabsf(d3) * RF;
        const float gx1 = u1 * a1, gy1 = v1 * a1;
        const float gx2 = u2 * a2, gy2 = v2 * a2;
        const float gx3 = u3 * a3, gy3 = v3 * a3;

        const float D0x = gx2 - gx1, D0y = gy2 - gy1, D0z = d2 - d1;
        const float D1x = gx3 - gx1, D1y = gy3 - gy1, D1z = d3 - d1;
        const float D2x = gx3 - gx2, D2y = gy3 - gy2, D2z = d3 - d2;

        const float e00 = D0x*D0x + D0y*D0y + D0z*D0z;
        const float e11 = D1x*D1x + D1y*D1y + D1z*D1z;
        const float e22 = D2x*D2x + D2y*D2y + D2z*D2z;
        const float e01 = D0x*D1x + D0y*D1y + D0z*D1z;
        const float e02 = D0x*D2x + D0y*D2y + D0z*D2z;
        const float e12 = D1x*D2x + D1y*D2y + D1z*D2z;
        const float n0 = sqrtf(e00), n1 = sqrtf(e11), n2 = sqrtf(e22);
        constexpr float DC = 0.867f;
        int cnt = 0;
        cnt += (fabsf(e00) > DC * (n0*n0 + 1e-8f));
        cnt += (fabsf(e11) > DC * (n1*n1 + 1e-8f));
        cnt += (fabsf(e22) > DC * (n2*n2 + 1e-8f));
        cnt += 2 * (fabsf(e01) > DC * (n0*n1 + 1e-8f));
        cnt += 2 * (fabsf(e02) > DC * (n0*n2 + 1e-8f));
        cnt += 2 * (fabsf(e12) > DC * (n1*n2 + 1e-8f));
        const bool mask_cos = cnt > 3;

        const bool mx = (fabsf(D0x) < 0.01f) | (fabsf(D1x) < 0.01f) | (fabsf(D2x) < 0.01f);
        const bool my = (fabsf(D0y) < 0.01f) | (fabsf(D1y) < 0.01f) | (fabsf(D2y) < 0.01f);
        const bool mz = (fabsf(D0z) < 0.01f) | (fabsf(D1z) < 0.01f) | (fabsf(D2z) < 0.01f);
        const bool mask = !((mx && my && mz) || mask_cos);

        // pred points
        const float b1s = fabsf(e1) * RF, b2s = fabsf(e2) * RF, b3s = fabsf(e3) * RF;
        float qx1 = u1 * b1s, qy1 = v1 * b1s, qz1 = e1;
        float qx2 = u2 * b2s, qy2 = v2 * b2s, qz2 = e2;
        float qx3 = u3 * b3s, qy3 = v3 * b3s, qz3 = e3;
        // replicate reference's zmask broadcast (coordinate ROW c, not point c)
        const bool zm0 = (qz1 == 0.0f), zm1 = (qz2 == 0.0f), zm2 = (qz3 == 0.0f);
        if (zm0) { qx1 = qx2 = qx3 = 1e-4f; }
        if (zm1) { qy1 = qy2 = qy3 = 1e-4f; }
        if (zm2) { qz1 = qz2 = qz3 = 1e-4f; }

        const float P0x = qx2 - qx1, P0y = qy2 - qy1, P0z = qz2 - qz1;
        const float Q1x = qx3 - qx1, Q1y = qy3 - qy1, Q1z = qz3 - qz1;

        const float gnx = D0y * D1z - D0z * D1y;
        const float gny = D0z * D1x - D0x * D1z;
        const float gnz = D0x * D1y - D0y * D1x;
        const float dnx = P0y * Q1z - P0z * Q1y;
        const float dny = P0z * Q1x - P0x * Q1z;
        const float dnz = P0x * Q1y - P0y * Q1x;

        float gnn = sqrtf(gnx*gnx + gny*gny + gnz*gnz);
        float dnn = sqrtf(dnx*dnx + dny*dny + dnz*dnz);
        if (gnn == 0.0f) gnn = 0.01f;
        if (dnn == 0.0f) dnn = 0.01f;
        const float rg = 1.0f / gnn, rd = 1.0f / dnn;
        const float L = fabsf(gnx*rg - dnx*rd) + fabsf(gny*rg - dny*rd) + fabsf(gnz*rg - dnz*rd);

        Lm[b * Gd + g] = mask ? L : -1.0f;
        if (mask) {
            ++lcnt;
            lsum += (double)L;
            atomicAdd(&lh[__float_as_uint(L) >> 20], 1u);
        }
    }

    ssum[t] = lsum; scnt[t] = lcnt;
    __syncthreads();
    for (int s = 128; s > 0; s >>= 1) {
        if (t < s) { ssum[t] += ssum[t + s]; scnt[t] += scnt[t + s]; }
        __syncthreads();
    }
    if (t == 0) {
        atomicAdd((double*)(ws + WS_SUM_ALL), ssum[0]);
        atomicAdd((unsigned*)(ws + WS_N), scnt[0]);
    }
    unsigned* __restrict__ h1 = (unsigned*)(ws + HIST1_OFF);
    for (int k = t; k < 4096; k += 256) {
        const unsigned c = lh[k];
        if (c) atomicAdd(&h1[k], c);
    }
}

// ---------------- kernel 2: select top-12-bit bin of the drop-th smallest ----------------
__global__ __launch_bounds__(256) void k_sel1(unsigned char* __restrict__ ws)
{
    __shared__ unsigned part[256];
    const int t = threadIdx.x;
    const unsigned n = *(const unsigned*)(ws + WS_N);
    const unsigned drop = n >> 2;
    if (t == 0) *(unsigned*)(ws + WS_DROP) = drop;
    if (drop == 0) {
        if (t == 0) {
            *(unsigned*)(ws + WS_BIN1) = 0xFFFFFFFFu;  // nothing matches in hist2
            *(unsigned*)(ws + WS_TGT1) = 0u;
        }
        return;
    }
    const unsigned* __restrict__ hist = (const unsigned*)(ws + HIST1_OFF);
    unsigned loc[16];
    unsigned s = 0;
#pragma unroll
    for (int k = 0; k < 16; ++k) { loc[k] = hist[t * 16 + k]; s += loc[k]; }
    part[t] = s;
    __syncthreads();
    for (int off = 1; off < 256; off <<= 1) {
        const unsigned add = (t >= off) ? part[t - off] : 0u;
        __syncthreads();
        part[t] += add;
        __syncthreads();
    }
    const unsigned incl = part[t];
    const unsigned excl = incl - s;
    if (incl >= drop && excl < drop) {
        unsigned cum = excl;
#pragma unroll
        for (int k = 0; k < 16; ++k) {
            const unsigned c = loc[k];
            if (cum + c >= drop) {
                *(unsigned*)(ws + WS_BIN1) = (unsigned)(t * 16 + k);
                *(unsigned*)(ws + WS_TGT1) = drop - cum;   // rank within bin1, >=1
                break;
            }
            cum += c;
        }
    }
}

// ---------------- kernel 3: hist of bits[19:8] within bin1 + per-bin sums + sum_less ----------------
__global__ __launch_bounds__(256) void k_hist2(unsigned char* __restrict__ ws)
{
    __shared__ unsigned c2[4096];
    __shared__ float    s2[4096];
    __shared__ double   sred[256];
    const int t = threadIdx.x;
    for (int k = t; k < 4096; k += 256) { c2[k] = 0u; s2[k] = 0.0f; }
    __syncthreads();

    const unsigned bin1 = *(const unsigned*)(ws + WS_BIN1);
    const float* __restrict__ Lm = (const float*)(ws + LM_OFF);
    const int stride = gridDim.x * 256;
    double dless = 0.0;
    for (int i = blockIdx.x * 256 + t; i < Nd; i += stride) {
        const unsigned u = __float_as_uint(Lm[i]);
        if (u & 0x80000000u) continue;          // unmasked
        const unsigned top = u >> 20;
        if (top < bin1) {
            dless += (double)__uint_as_float(u);
        } else if (top == bin1) {
            const int k = (u >> 8) & 0xFFF;
            atomicAdd(&c2[k], 1u);
            atomicAdd(&s2[k], __uint_as_float(u));
        }
    }
    sred[t] = dless;
    __syncthreads();
    for (int s = 128; s > 0; s >>= 1) {
        if (t < s) sred[t] += sred[t + s];
        __syncthreads();
    }
    if (t == 0) atomicAdd((double*)(ws + WS_SUM_LESS), sred[0]);

    unsigned* __restrict__ gc = (unsigned*)(ws + H2C_OFF);
    double*   __restrict__ gs = (double*)(ws + H2S_OFF);
    for (int k = t; k < 4096; k += 256) {
        const unsigned c = c2[k];
        if (c) { atomicAdd(&gc[k], c); atomicAdd(&gs[k], (double)s2[k]); }
    }
}

// ---------------- kernel 4: second-level select + finalize ----------------
__global__ __launch_bounds__(256) void k_sel2_fin(unsigned char* __restrict__ ws,
                                                  float* __restrict__ out)
{
    __shared__ unsigned pc[256];
    __shared__ double   ps[256];
    const int t = threadIdx.x;
    const unsigned n    = *(const unsigned*)(ws + WS_N);
    const unsigned drop = *(const unsigned*)(ws + WS_DROP);
    const double sum_all = *(const double*)(ws + WS_SUM_ALL);
    const unsigned keep = n - drop;
    const double denom = (double)(keep > 0u ? keep : 1u);

    if (drop == 0) {
        if (t == 0) out[0] = (float)(sum_all / denom);
        return;
    }
    const unsigned bin1 = *(const unsigned*)(ws + WS_BIN1);
    const unsigned tgt1 = *(const unsigned*)(ws + WS_TGT1);
    const double sum_less = *(const double*)(ws + WS_SUM_LESS);

    const unsigned* __restrict__ gc = (const unsigned*)(ws + H2C_OFF);
    const double*   __restrict__ gs = (const double*)(ws + H2S_OFF);
    unsigned lc[16]; double lsv[16];
    unsigned cs = 0; double ss = 0.0;
#pragma unroll
    for (int k = 0; k < 16; ++k) {
        lc[k] = gc[t * 16 + k]; lsv[k] = gs[t * 16 + k];
        cs += lc[k]; ss += lsv[k];
    }
    pc[t] = cs; ps[t] = ss;
    __syncthreads();
    for (int off = 1; off < 256; off <<= 1) {
        const unsigned addc = (t >= off) ? pc[t - off] : 0u;
        const double   adds = (t >= off) ? ps[t - off] : 0.0;
        __syncthreads();
        pc[t] += addc; ps[t] += adds;
        __syncthreads();
    }
    const unsigned inclc = pc[t];
    const unsigned exclc = inclc - cs;
    if (inclc >= tgt1 && exclc < tgt1) {
        unsigned cum = exclc;
        double scum = ps[t] - ss;   // sums of all bins before this thread's chunk
        for (int k = 0; k < 16; ++k) {
            const unsigned c = lc[k];
            if (cum + c >= tgt1) {
                const unsigned bin2 = (unsigned)(t * 16 + k);
                const unsigned tgt2 = tgt1 - cum;   // items to take inside bin2
                // value of the 24-bit prefix lower edge (rel. err <= 2^-15 per item)
                const float v_lo = __uint_as_float((bin1 << 20) | (bin2 << 8));
                const double dropped = sum_less + scum + (double)tgt2 * (double)v_lo;
                out[0] = (float)((sum_all - dropped) / denom);
                break;
            }
            cum += c;
            scum += lsv[k];
        }
    }
}

extern "C" void kernel_launch(void* const* d_in, const int* in_sizes, int n_in,
                              void* d_out, int out_size, void* d_ws, size_t ws_size,
                              hipStream_t stream)
{
    const float* gt  = (const float*)d_in[0];
    const float* pd  = (const float*)d_in[1];
    const int*   p1x = (const int*)d_in[2];
    const int*   p1y = (const int*)d_in[3];
    const int*   p2x = (const int*)d_in[4];
    const int*   p2y = (const int*)d_in[5];
    const int*   p3x = (const int*)d_in[6];
    const int*   p3y = (const int*)d_in[7];
    unsigned char* ws = (unsigned char*)d_ws;
    float* out = (float*)d_out;

    hipMemsetAsync(ws, 0, CTRL_BYTES, stream);
    k_pack    <<<dim3(GRIDP), dim3(256), 0, stream>>>(gt, pd, (float*)(ws + PACK_OFF));
    k_compute <<<dim3(GRID1), dim3(256), 0, stream>>>(p1x, p1y, p2x, p2y, p3x, p3y, ws);
    k_sel1    <<<dim3(1),     dim3(256), 0, stream>>>(ws);
    k_hist2   <<<dim3(GRID1), dim3(256), 0, stream>>>(ws);
    k_sel2_fin<<<dim3(1),     dim3(256), 0, stream>>>(ws, out);
}